// Round 5
// baseline (79.918 us; speedup 1.0000x reference)
//
#include <hip/hip_runtime.h>

// Problem constants
#define BB 32
#define KK 5
#define TT 20
#define VV 9488
#define HH 1024

// Output layout (floats), concatenated in return order:
// out0 beam_seq          : [0,        3360)
// out1 beam_seq_logprobs : [3360,     31883040)
// out2 beam_logprobs_sum : [31883040, 31883200)
// out3 new_state         : [31883200, 32210880)
#define OFF1 3360
#define OFF2 31883040
#define OFF3 31883200

typedef float f4 __attribute__((ext_vector_type(4)));

__device__ __forceinline__ bool better(float av, int ai, float bv, int bi) {
    // total order: value descending, then index ascending (jax top_k tie-break)
    return (av > bv) || (av == bv && ai < bi);
}

// Branch-free descending insert of (val,idx) into sorted 5-list. Static indices only.
__device__ __forceinline__ void insert5(float tv[5], int ti[5], float val, int idx) {
#pragma unroll
    for (int j = 4; j >= 1; --j) {
        bool bj  = better(val, idx, tv[j],   ti[j]);
        bool bj1 = better(val, idx, tv[j-1], ti[j-1]);
        float nv = bj ? (bj1 ? tv[j-1] : val) : tv[j];
        int   ni = bj ? (bj1 ? ti[j-1] : idx) : ti[j];
        tv[j] = nv; ti[j] = ni;
    }
    bool b0 = better(val, idx, tv[0], ti[0]);
    ti[0] = b0 ? idx : ti[0];
    tv[0] = b0 ? val : tv[0];
}

// Merge two descending sorted 5-lists, keep top-5. Static indices only:
// merged[n] = worst over {i+j==n} of best(A[i], B[j]).
__device__ __forceinline__ void merge_sorted5(float av[5], int ai[5],
                                              const float bv[5], const int bi[5]) {
    float ov[5]; int oi[5];
#pragma unroll
    for (int n = 0; n < 5; ++n) {
        float mv = 0.f; int mi = 0;
#pragma unroll
        for (int i = 0; i <= n; ++i) {
            const int j = n - i;
            float cv; int ci;
            if (better(av[i], ai[i], bv[j], bi[j])) { cv = av[i]; ci = ai[i]; }
            else                                    { cv = bv[j]; ci = bi[j]; }
            if (i == 0 || better(mv, mi, cv, ci)) { mv = cv; mi = ci; }  // keep worst
        }
        ov[n] = mv; oi[n] = mi;
    }
#pragma unroll
    for (int n = 0; n < 5; ++n) { av[n] = ov[n]; ai[n] = oi[n]; }
}

// Shuffle-allreduce merge: after rounds, all lanes in each 2*MAXST-lane group
// hold the group's merged top-5.
template<int MAXST>
__device__ __forceinline__ void wave_merge(float tv[5], int ti[5]) {
#pragma unroll
    for (int st = 1; st <= MAXST; st <<= 1) {
        float bv[5]; int bi[5];
#pragma unroll
        for (int j = 0; j < 5; ++j) {
            bv[j] = __shfl_xor(tv[j], st);
            bi[j] = __shfl_xor(ti[j], st);
        }
        merge_sorted5(tv, ti, bv, bi);
    }
}

// Single fused top-k: 32 blocks x 1024 threads. Per-thread scan (~46 cands),
// in-wave shuffle merge, 16-wave LDS merge by wave 0.
__global__ __launch_bounds__(1024) void topk_kernel(
    const float* __restrict__ logprobs,      // (B*K, V)
    const float* __restrict__ sums,          // (B, K)
    int*   __restrict__ ws_beam,             // (B*K)
    int*   __restrict__ ws_sel,              // (B*K)
    float* __restrict__ ws_sum)              // (B*K)
{
    const int b   = blockIdx.x;
    const int tid = threadIdx.x;

    float tv[5]; int ti[5];
#pragma unroll
    for (int j = 0; j < 5; ++j) { tv[j] = -INFINITY; ti[j] = 0x7FFFFF00 + j; }

#pragma unroll
    for (int k = 0; k < KK; ++k) {
        const float s = sums[b * KK + k];
        const float* lp = logprobs + (size_t)(b * KK + k) * VV;
        for (int v = tid; v < VV; v += 1024)
            insert5(tv, ti, s + lp[v], k * VV + v);
    }

    wave_merge<32>(tv, ti);   // all 64 lanes hold their wave's top-5

    __shared__ float lv[16][5];
    __shared__ int   li[16][5];
    const int wid = tid >> 6, lane = tid & 63;
    if (lane == 0) {
#pragma unroll
        for (int j = 0; j < 5; ++j) { lv[wid][j] = tv[j]; li[wid][j] = ti[j]; }
    }
    __syncthreads();
    if (tid < 64) {
        if (tid < 16) {
#pragma unroll
            for (int j = 0; j < 5; ++j) { tv[j] = lv[tid][j]; ti[j] = li[tid][j]; }
        } else {
#pragma unroll
            for (int j = 0; j < 5; ++j) { tv[j] = -INFINITY; ti[j] = 0x7FFFFF00 + j; }
        }
        wave_merge<8>(tv, ti);   // lanes 0..15 merged
        if (tid == 0) {
#pragma unroll
            for (int j = 0; j < 5; ++j) {
                const int idx  = ti[j];
                const int beam = idx / VV;
                ws_beam[b * KK + j] = beam;
                ws_sel [b * KK + j] = idx - beam * VV;
                ws_sum [b * KK + j] = tv[j];
            }
        }
    }
}

// Copy/scatter: 2-deep pipelined float4 copy per row.
__global__ __launch_bounds__(256) void scatter_kernel(
    const float* __restrict__ logprobs,      // (B*K, V)
    const int*   __restrict__ beam_seq_in,   // (B, K, T)
    const float* __restrict__ bslp_in,       // (B, K, T, V)
    const float* __restrict__ state_in,      // (2, B*K, H)
    const int*   __restrict__ ws_beam,
    const int*   __restrict__ ws_sel,
    const float* __restrict__ ws_sum,
    float* __restrict__ out)
{
    const int bid = blockIdx.x;
    const int tid = threadIdx.x;
    const int NROWS = BB * KK * (TT + 1);    // 3360
    const int NF4   = VV / 4;                // 2372

    if (bid < NROWS) {
        // one 9488-float row of beam_seq_logprobs output
        const int b   = bid / (KK * (TT + 1));
        const int rem = bid % (KK * (TT + 1));
        const int k   = rem / (TT + 1);
        const int t   = rem % (TT + 1);
        const int beam = ws_beam[b * KK + k];
        const float* src = (t < TT)
            ? bslp_in  + ((size_t)((b * KK + beam) * TT + t)) * VV
            : logprobs + (size_t)(b * KK + beam) * VV;
        const f4* s4 = (const f4*)src;
        f4* d4 = (f4*)(out + OFF1 + (size_t)bid * VV);
        // 2-deep software pipeline: two independent loads in flight per iter
        int i = tid;
        for (; i + 256 < NF4; i += 512) {
            f4 a = s4[i];
            f4 c = s4[i + 256];
            d4[i] = a;
            d4[i + 256] = c;
        }
        if (i < NF4) d4[i] = s4[i];
    } else if (bid < NROWS + 2 * BB * KK) {
        // one 1024-float row of new_state: exactly one float4 per thread
        const int r = bid - NROWS;
        const int s = r / (BB * KK);
        const int i = r % (BB * KK);
        const int b = i / KK;
        const int beam = ws_beam[i];
        const f4* s4 = (const f4*)(state_in + ((size_t)s * (BB * KK) + b * KK + beam) * HH);
        f4* d4 = (f4*)(out + OFF3 + (size_t)r * HH);
        d4[tid] = s4[tid];
    } else {
        // small outputs: beam_seq (as float) and beam_logprobs_sum
        for (int j = tid; j < NROWS; j += 256) {
            const int b   = j / (KK * (TT + 1));
            const int rem = j % (KK * (TT + 1));
            const int k   = rem / (TT + 1);
            const int t   = rem % (TT + 1);
            const int bk  = b * KK + k;
            int val;
            if (t < TT) val = beam_seq_in[(size_t)(b * KK + ws_beam[bk]) * TT + t];
            else        val = ws_sel[bk];
            out[j] = (float)val;
        }
        for (int j = tid; j < BB * KK; j += 256) out[OFF2 + j] = ws_sum[j];
    }
}

extern "C" void kernel_launch(void* const* d_in, const int* in_sizes, int n_in,
                              void* d_out, int out_size, void* d_ws, size_t ws_size,
                              hipStream_t stream) {
    const float* logprobs = (const float*)d_in[0];
    const int*   beam_seq = (const int*)  d_in[1];
    const float* bslp     = (const float*)d_in[2];
    const float* sums     = (const float*)d_in[3];
    const float* state    = (const float*)d_in[4];

    int*   ws_beam = (int*)d_ws;
    int*   ws_sel  = ws_beam + BB * KK;
    float* ws_sum  = (float*)(ws_sel + BB * KK);
    float* out     = (float*)d_out;

    topk_kernel<<<BB, 1024, 0, stream>>>(logprobs, sums, ws_beam, ws_sel, ws_sum);

    const int nblocks = 3360 + 320 + 1;   // bslp rows + state rows + small-out block
    scatter_kernel<<<nblocks, 256, 0, stream>>>(logprobs, beam_seq, bslp, state,
                                                ws_beam, ws_sel, ws_sum, out);
}

// Round 6
// 58.719 us; speedup vs baseline: 1.3610x; 1.3610x over previous
//
#include <hip/hip_runtime.h>

// Problem constants
#define BB 32
#define KK 5
#define TT 20
#define VV 9488
#define HH 1024
#define NSPLIT 16
#define CHUNK (VV / NSPLIT)   // 593 exactly

// Output layout (floats), concatenated in return order:
// out0 beam_seq          : [0,        3360)
// out1 beam_seq_logprobs : [3360,     31883040)
// out2 beam_logprobs_sum : [31883040, 31883200)
// out3 new_state         : [31883200, 32210880)
#define OFF1 3360
#define OFF2 31883040
#define OFF3 31883200

#define N1F4 7969920          // 3360 rows * 2372 f4 per row
#define NSF4 81920            // 320 rows * 256 f4 per row
#define TOTF4 (N1F4 + NSF4)   // 8051840

typedef float f4 __attribute__((ext_vector_type(4)));
typedef unsigned long long u64;

__device__ __forceinline__ bool better(float av, int ai, float bv, int bi) {
    // total order: value descending, then index ascending (jax top_k tie-break)
    return (av > bv) || (av == bv && ai < bi);
}

// ---------------- Phase 1: per-(batch, v-slice) partial top-5 ----------------
// 512 blocks x 256. Branchy insert: the guard comparison is ~1 op/candidate and
// almost always false (only ~5/593 inserts), far cheaper than branch-free.
__global__ __launch_bounds__(256) void topk_part_kernel(
    const float* __restrict__ logprobs,      // (B*K, V)
    const float* __restrict__ sums,          // (B, K)
    float* __restrict__ pv,                  // (B*NSPLIT, 5)
    int*   __restrict__ pi)
{
    const int b    = blockIdx.x / NSPLIT;
    const int part = blockIdx.x % NSPLIT;
    const int tid  = threadIdx.x;
    const int v0   = part * CHUNK;

    float tv[5]; int ti[5];
#pragma unroll
    for (int j = 0; j < 5; ++j) { tv[j] = -INFINITY; ti[j] = 0x7FFFFF00 + j; }

    for (int k = 0; k < KK; ++k) {
        const float s = sums[b * KK + k];
        const float* lp = logprobs + (size_t)(b * KK + k) * VV;
        for (int v = v0 + tid; v < v0 + CHUNK; v += 256) {
            const float val = s + lp[v];
            const int idx = k * VV + v;
            if (better(val, idx, tv[4], ti[4])) {
                int pos = 4;
#pragma unroll
                for (int j = 3; j >= 0; --j)
                    if (better(val, idx, tv[j], ti[j])) pos = j;
#pragma unroll
                for (int j = 4; j > 0; --j) {
                    if (j > pos) { tv[j] = tv[j-1]; ti[j] = ti[j-1]; }
                }
                tv[pos] = val; ti[pos] = idx;
            }
        }
    }

    __shared__ float sv[256 * 5];
    __shared__ int   si[256 * 5];

    for (int stride = 128; stride >= 1; stride >>= 1) {
        if (tid >= stride && tid < 2 * stride) {
#pragma unroll
            for (int j = 0; j < 5; ++j) { sv[tid*5+j] = tv[j]; si[tid*5+j] = ti[j]; }
        }
        __syncthreads();
        if (tid < stride) {
            float bv[5]; int bi[5];
#pragma unroll
            for (int j = 0; j < 5; ++j) { bv[j] = sv[(tid+stride)*5+j]; bi[j] = si[(tid+stride)*5+j]; }
            float ov[5]; int oi[5];
            int ia = 0, ib = 0;
#pragma unroll
            for (int n = 0; n < 5; ++n) {
                if (better(tv[ia], ti[ia], bv[ib], bi[ib])) { ov[n] = tv[ia]; oi[n] = ti[ia]; ++ia; }
                else                                        { ov[n] = bv[ib]; oi[n] = bi[ib]; ++ib; }
            }
#pragma unroll
            for (int j = 0; j < 5; ++j) { tv[j] = ov[j]; ti[j] = oi[j]; }
        }
        __syncthreads();
    }

    if (tid == 0) {
#pragma unroll
        for (int j = 0; j < 5; ++j) {
            pv[(size_t)blockIdx.x * 5 + j] = tv[j];
            pi[(size_t)blockIdx.x * 5 + j] = ti[j];
        }
    }
}

// Merge two descending sorted 5-lists, keep top-5. Static indices only.
__device__ __forceinline__ void merge_sorted5(float av[5], int ai[5],
                                              const float bv[5], const int bi[5]) {
    float ov[5]; int oi[5];
#pragma unroll
    for (int n = 0; n < 5; ++n) {
        float mv = 0.f; int mi = 0;
#pragma unroll
        for (int i = 0; i <= n; ++i) {
            const int j = n - i;
            float cv; int ci;
            if (better(av[i], ai[i], bv[j], bi[j])) { cv = av[i]; ci = ai[i]; }
            else                                    { cv = bv[j]; ci = bi[j]; }
            if (i == 0 || better(mv, mi, cv, ci)) { mv = cv; mi = ci; }  // keep worst
        }
        ov[n] = mv; oi[n] = mi;
    }
#pragma unroll
    for (int n = 0; n < 5; ++n) { av[n] = ov[n]; ai[n] = oi[n]; }
}

// ---------------- Phase 2: final merge + small outputs + src-address tables ---
// 32 blocks x 64. Produces: out0 (beam_seq), out2 (beam_logprobs_sum), and a
// 64-bit source pointer per big output row so the copy kernel has NO prologue.
__global__ __launch_bounds__(64) void merge_kernel(
    const float* __restrict__ pv,
    const int*   __restrict__ pi,
    const float* __restrict__ logprobs,      // (B*K, V)
    const int*   __restrict__ beam_seq_in,   // (B, K, T)
    const float* __restrict__ bslp_in,       // (B, K, T, V)
    const float* __restrict__ state_in,      // (2, B*K, H)
    u64* __restrict__ srcrow,                // [3360] src addr per out1 row
    u64* __restrict__ srcst,                 // [320]  src addr per state row
    float* __restrict__ out)
{
    const int b   = blockIdx.x;
    const int tid = threadIdx.x;

    float tv[5]; int ti[5];
    if (tid < NSPLIT) {
        const size_t base = ((size_t)b * NSPLIT + tid) * 5;
#pragma unroll
        for (int j = 0; j < 5; ++j) { tv[j] = pv[base + j]; ti[j] = pi[base + j]; }
    } else {
#pragma unroll
        for (int j = 0; j < 5; ++j) { tv[j] = -INFINITY; ti[j] = 0x7FFFFF00 + j; }
    }

    // shuffle-allreduce within the first 16 lanes, then broadcast lane 0
#pragma unroll
    for (int st = 1; st <= 8; st <<= 1) {
        float bv[5]; int bi[5];
#pragma unroll
        for (int j = 0; j < 5; ++j) {
            bv[j] = __shfl_xor(tv[j], st);
            bi[j] = __shfl_xor(ti[j], st);
        }
        merge_sorted5(tv, ti, bv, bi);
    }
#pragma unroll
    for (int j = 0; j < 5; ++j) {
        tv[j] = __shfl(tv[j], 0);
        ti[j] = __shfl(ti[j], 0);
    }
    // every lane now holds the final top-5 for batch b
    int beam[5], sel[5];
#pragma unroll
    for (int j = 0; j < 5; ++j) { beam[j] = ti[j] / VV; sel[j] = ti[j] - beam[j] * VV; }

    // out1 source-row table + beam_seq output (105 rows per batch)
    for (int rr = tid; rr < KK * (TT + 1); rr += 64) {
        const int k = rr / (TT + 1), t = rr % (TT + 1);
        int bm = 0, sl = 0;
#pragma unroll
        for (int j = 0; j < 5; ++j) if (k == j) { bm = beam[j]; sl = sel[j]; }
        const float* src = (t < TT)
            ? bslp_in  + ((size_t)((b * KK + bm) * TT + t)) * VV
            : logprobs + (size_t)(b * KK + bm) * VV;
        srcrow[b * KK * (TT + 1) + rr] = (u64)(uintptr_t)src;
        const int val = (t < TT) ? beam_seq_in[(size_t)(b * KK + bm) * TT + t] : sl;
        out[(size_t)b * KK * (TT + 1) + rr] = (float)val;
    }

    // state source-row table (2 x 5 rows per batch)
    if (tid < 10) {
        const int s = tid / 5, k = tid % 5;
        int bm = 0;
#pragma unroll
        for (int j = 0; j < 5; ++j) if (k == j) bm = beam[j];
        srcst[s * (BB * KK) + b * KK + k] =
            (u64)(uintptr_t)(state_in + ((size_t)s * (BB * KK) + b * KK + bm) * HH);
    }

    // beam_logprobs_sum output
    if (tid == 0) {
#pragma unroll
        for (int j = 0; j < 5; ++j) out[OFF2 + b * KK + j] = tv[j];
    }
}

// ---------------- Phase 3: flat grid-stride float4 copy ----------------------
// Pure copy-ubench structure: one linear f4 index space, no per-block prologue.
__global__ __launch_bounds__(256) void copy_kernel(
    const u64* __restrict__ srcrow,
    const u64* __restrict__ srcst,
    float* __restrict__ out)
{
    f4* __restrict__ dst1 = (f4*)(out + OFF1);
    f4* __restrict__ dst3 = (f4*)(out + OFF3);
    const int stride = gridDim.x * 256;
    for (int idx = blockIdx.x * 256 + threadIdx.x; idx < TOTF4; idx += stride) {
        if (idx < N1F4) {
            const unsigned row = (unsigned)idx / 2372u;       // magic-mul division
            const unsigned col = (unsigned)idx - row * 2372u;
            const f4* __restrict__ s = (const f4*)(uintptr_t)srcrow[row];
            dst1[idx] = s[col];
        } else {
            const int j = idx - N1F4;
            const int r = j >> 8, col = j & 255;
            const f4* __restrict__ s = (const f4*)(uintptr_t)srcst[r];
            dst3[j] = s[col];
        }
    }
}

extern "C" void kernel_launch(void* const* d_in, const int* in_sizes, int n_in,
                              void* d_out, int out_size, void* d_ws, size_t ws_size,
                              hipStream_t stream) {
    const float* logprobs = (const float*)d_in[0];
    const int*   beam_seq = (const int*)  d_in[1];
    const float* bslp     = (const float*)d_in[2];
    const float* sums     = (const float*)d_in[3];
    const float* state    = (const float*)d_in[4];

    // ws layout: 8B-aligned tables first, then pv/pi
    u64*   srcrow = (u64*)d_ws;                       // 3360 entries
    u64*   srcst  = srcrow + BB * KK * (TT + 1);      // 320 entries
    float* pv     = (float*)(srcst + 2 * BB * KK);    // 2560 floats
    int*   pi     = (int*)(pv + BB * NSPLIT * 5);     // 2560 ints
    float* out    = (float*)d_out;

    topk_part_kernel<<<BB * NSPLIT, 256, 0, stream>>>(logprobs, sums, pv, pi);
    merge_kernel<<<BB, 64, 0, stream>>>(pv, pi, logprobs, beam_seq, bslp, state,
                                        srcrow, srcst, out);
    copy_kernel<<<2048, 256, 0, stream>>>(srcrow, srcst, out);
}